// Round 9
// baseline (197.143 us; speedup 1.0000x reference)
//
#include <hip/hip_runtime.h>
#include <hip/hip_bf16.h>
#include <cstdint>
#include <cstddef>

// ---------------------------------------------------------------------------
// MultiHeadAttention  B=2 S=2048 E=1024 H=16 D=64 causal, bf16 MFMA path.
// k_prep -> qkv gemm (ring-3 BK=32) -> flash attn (one 64-row strip/block,
// grid 1024 longest-first, ring-2 LDS = 5 blocks/CU) -> out gemm (ring-3).
// ---------------------------------------------------------------------------

typedef unsigned short u16;
typedef __attribute__((ext_vector_type(8))) short short8;
typedef __attribute__((ext_vector_type(4))) short short4v;
typedef __attribute__((ext_vector_type(4))) float floatx4;

#define MFMA16(a, b, c) __builtin_amdgcn_mfma_f32_16x16x32_bf16((a), (b), (c), 0, 0, 0)

#if __has_builtin(__builtin_amdgcn_mfma_f32_16x16x16_bf16)
#define PV_MFMA(a, b, c) __builtin_amdgcn_mfma_f32_16x16x16_bf16((a), (b), (c), 0, 0, 0)
#elif __has_builtin(__builtin_amdgcn_mfma_f32_16x16x16bf16_1k)
#define PV_MFMA(a, b, c) __builtin_amdgcn_mfma_f32_16x16x16bf16_1k((a), (b), (c), 0, 0, 0)
#else
static __device__ __forceinline__ floatx4 pv_mfma_asm(short4v a, short4v b, floatx4 c) {
    asm volatile("v_mfma_f32_16x16x16_bf16 %0, %1, %2, %0" : "+v"(c) : "v"(a), "v"(b));
    return c;
}
#define PV_MFMA(a, b, c) pv_mfma_asm((a), (b), (c))
#endif

#if __has_builtin(__builtin_amdgcn_exp2f)
#define EXP2(x) __builtin_amdgcn_exp2f(x)
#else
#define EXP2(x) exp2f(x)
#endif

#define QSCALE 0.18033688011f  // 0.125 * log2(e)
#define NEGINF (-__builtin_inff())

static __device__ __forceinline__ u16 f2b(float f) {
    union { float f; uint32_t u; } v; v.f = f;
    return (u16)((v.u + 0x7fffu + ((v.u >> 16) & 1u)) >> 16);  // RNE
}

static __device__ __forceinline__ uint32_t pkbf(float lo, float hi) {
    union { float f; uint32_t u; } a, b; a.f = lo; b.f = hi;
    return __builtin_amdgcn_perm(b.u + 0x8000u, a.u + 0x8000u, 0x07060302u);
}

static __device__ __forceinline__ void async_cp16(const u16* g, u16* lds_wave_base) {
    __builtin_amdgcn_global_load_lds((__attribute__((address_space(1))) void*)g,
                                     (__attribute__((address_space(3))) void*)lds_wave_base,
                                     16, 0, 0);
}

// ---------------- fused prep: x->bf16, W_qkv^T->bf16, W_out^T->bf16 ---------

__global__ __launch_bounds__(256) void k_prep(const float* __restrict__ x,
                                              const float* __restrict__ Wq,
                                              const float* __restrict__ Wo,
                                              u16* __restrict__ xb,
                                              u16* __restrict__ wqkvT,
                                              u16* __restrict__ woutT) {
    int bx = blockIdx.x, tid = threadIdx.x;
    if (bx < 2048) {
        int g = bx * 256 + tid;
        const float4* s = (const float4*)x + (size_t)g * 2;
        float4 f0 = s[0], f1 = s[1];
        uint4 r;
        r.x = pkbf(f0.x, f0.y);
        r.y = pkbf(f0.z, f0.w);
        r.z = pkbf(f1.x, f1.y);
        r.w = pkbf(f1.z, f1.w);
        *(uint4*)(xb + (size_t)g * 8) = r;
        return;
    }
    __shared__ float t[32][33];
    const float* src;
    u16* dst;
    int R, C, b;
    if (bx < 5120) { b = bx - 2048; src = Wq; dst = wqkvT; R = 1024; C = 3072; }
    else           { b = bx - 5120; src = Wo; dst = woutT; R = 1024; C = 1024; }
    int nbx = C >> 5;
    int yq = b / nbx, xq = b - yq * nbx;
    int c0 = xq * 32, r0 = yq * 32;
    int tx = tid & 31, ty = tid >> 5;
#pragma unroll
    for (int i = 0; i < 4; ++i)
        t[ty + i * 8][tx] = src[(size_t)(r0 + ty + i * 8) * C + c0 + tx];
    __syncthreads();
#pragma unroll
    for (int i = 0; i < 4; ++i)
        dst[(size_t)(c0 + ty + i * 8) * R + r0 + tx] = f2b(t[tx][ty + i * 8]);
}

// ---------------- qkv GEMM: 128x128, BK=32, ring-3 pipeline -----------------

__global__ __launch_bounds__(256, 3) void k_qkv_gemm(const u16* __restrict__ A,
                                                     const u16* __restrict__ Bt,
                                                     const float* __restrict__ bias,
                                                     u16* __restrict__ Qb,
                                                     u16* __restrict__ Kb,
                                                     u16* __restrict__ Vtb) {
    __shared__ __align__(16) u16 As[3][128 * 32];
    __shared__ __align__(16) u16 Bs[3][128 * 32];
    int tid = threadIdx.x;
    int w = tid >> 6, lane = tid & 63, quad = lane >> 4, l16 = lane & 15;
    int wm = w >> 1, wn = w & 1;
    int m0 = blockIdx.y * 128, n0 = blockIdx.x * 128;
    int wb = (tid & ~63) * 8;

    int ra0 = tid >> 2, ca0 = (tid & 3) * 8;
    int ra1 = (256 + tid) >> 2, ca1 = (tid & 3) * 8;
    const u16* A0 = &A[(size_t)(m0 + ra0) * 1024 + ca0];
    const u16* A1 = &A[(size_t)(m0 + ra1) * 1024 + ca1];
    const u16* B0 = &Bt[(size_t)(n0 + ra0) * 1024 + ca0];
    const u16* B1 = &Bt[(size_t)(n0 + ra1) * 1024 + ca1];

    auto stage = [&](int src_kt, int slot) {
        int ko = src_kt * 32;
        async_cp16(A0 + ko, &As[slot][wb]);
        async_cp16(A1 + ko, &As[slot][2048 + wb]);
        async_cp16(B0 + ko, &Bs[slot][wb]);
        async_cp16(B1 + ko, &Bs[slot][2048 + wb]);
    };

    floatx4 acc[4][4] = {};
    stage(0, 0);
    stage(1, 1);

    for (int kt = 0; kt < 32; ++kt) {
        asm volatile("s_waitcnt vmcnt(4)" ::: "memory");
        asm volatile("s_barrier" ::: "memory");
        int jn = kt + 2;
        stage(jn < 32 ? jn : 31, jn % 3);
        int s = kt % 3;
        short8 af[4], bf[4];
#pragma unroll
        for (int mt = 0; mt < 4; ++mt)
            af[mt] = *(const short8*)&As[s][(wm * 64 + mt * 16 + l16) * 32 + quad * 8];
#pragma unroll
        for (int nt = 0; nt < 4; ++nt)
            bf[nt] = *(const short8*)&Bs[s][(wn * 64 + nt * 16 + l16) * 32 + quad * 8];
#pragma unroll
        for (int mt = 0; mt < 4; ++mt)
#pragma unroll
            for (int nt = 0; nt < 4; ++nt)
                acc[mt][nt] = MFMA16(af[mt], bf[nt], acc[mt][nt]);
    }

    int region = n0 >> 10;  // 0=Q 1=K 2=V
    if (region == 2) {
#pragma unroll
        for (int mt = 0; mt < 4; ++mt)
#pragma unroll
            for (int nt = 0; nt < 4; ++nt) {
                int n_abs = n0 + wn * 64 + nt * 16 + l16;
                int e = n_abs & 1023, h = e >> 6, d = e & 63;
                float vb = bias[n_abs];
                int mrow = m0 + wm * 64 + mt * 16 + quad * 4;
                int b = mrow >> 11, s0 = mrow & 2047;
                uint2 val;
                val.x = pkbf(acc[mt][nt][0] + vb, acc[mt][nt][1] + vb);
                val.y = pkbf(acc[mt][nt][2] + vb, acc[mt][nt][3] + vb);
                *(uint2*)&Vtb[((size_t)(b * 16 + h) * 64 + d) * 2048 + s0] = val;
            }
    } else {
        u16* dst = region == 0 ? Qb : Kb;
        float scl = region == 0 ? QSCALE : 1.0f;
#pragma unroll
        for (int mt = 0; mt < 4; ++mt)
#pragma unroll
            for (int nt = 0; nt < 4; ++nt)
#pragma unroll
                for (int r = 0; r < 4; ++r) {
                    int m_abs = m0 + wm * 64 + mt * 16 + quad * 4 + r;
                    int n_abs = n0 + wn * 64 + nt * 16 + l16;
                    float val = (acc[mt][nt][r] + bias[n_abs]) * scl;
                    int e = n_abs & 1023, h = e >> 6, d = e & 63;
                    int b = m_abs >> 11, s = m_abs & 2047;
                    dst[((size_t)(b * 16 + h) * 2048 + s) * 64 + d] = f2b(val);
                }
    }
}

// ---------------- out GEMM: 64x128, BK=32, ring-3 pipeline ------------------

__global__ __launch_bounds__(256, 4) void k_out_gemm(const u16* __restrict__ A,
                                                     const u16* __restrict__ Bt,
                                                     const float* __restrict__ bias,
                                                     float* __restrict__ out) {
    __shared__ __align__(16) u16 As[3][64 * 32];
    __shared__ __align__(16) u16 Bs[3][128 * 32];
    int tid = threadIdx.x;
    int w = tid >> 6, lane = tid & 63, quad = lane >> 4, l16 = lane & 15;
    int wm = w >> 1, wn = w & 1;
    int m0 = blockIdx.y * 64, n0 = blockIdx.x * 128;
    int wb = (tid & ~63) * 8;

    int ra0 = tid >> 2, ca0 = (tid & 3) * 8;
    int ra1 = (256 + tid) >> 2;
    const u16* A0 = &A[(size_t)(m0 + ra0) * 1024 + ca0];
    const u16* B0 = &Bt[(size_t)(n0 + ra0) * 1024 + ca0];
    const u16* B1 = &Bt[(size_t)(n0 + ra1) * 1024 + ca0];

    auto stage = [&](int src_kt, int slot) {
        int ko = src_kt * 32;
        async_cp16(A0 + ko, &As[slot][wb]);
        async_cp16(B0 + ko, &Bs[slot][wb]);
        async_cp16(B1 + ko, &Bs[slot][2048 + wb]);
    };

    floatx4 acc[2][4] = {};
    stage(0, 0);
    stage(1, 1);

    for (int kt = 0; kt < 32; ++kt) {
        asm volatile("s_waitcnt vmcnt(3)" ::: "memory");
        asm volatile("s_barrier" ::: "memory");
        int jn = kt + 2;
        stage(jn < 32 ? jn : 31, jn % 3);
        int s = kt % 3;
        short8 af[2], bf[4];
#pragma unroll
        for (int mt = 0; mt < 2; ++mt)
            af[mt] = *(const short8*)&As[s][(wm * 32 + mt * 16 + l16) * 32 + quad * 8];
#pragma unroll
        for (int nt = 0; nt < 4; ++nt)
            bf[nt] = *(const short8*)&Bs[s][(wn * 64 + nt * 16 + l16) * 32 + quad * 8];
#pragma unroll
        for (int mt = 0; mt < 2; ++mt)
#pragma unroll
            for (int nt = 0; nt < 4; ++nt)
                acc[mt][nt] = MFMA16(af[mt], bf[nt], acc[mt][nt]);
    }

#pragma unroll
    for (int mt = 0; mt < 2; ++mt)
#pragma unroll
        for (int nt = 0; nt < 4; ++nt)
#pragma unroll
            for (int r = 0; r < 4; ++r) {
                int m_abs = m0 + wm * 32 + mt * 16 + quad * 4 + r;
                int n_abs = n0 + wn * 64 + nt * 16 + l16;
                out[(size_t)m_abs * 1024 + n_abs] = acc[mt][nt][r] + bias[n_abs];
            }
}

// ---------------- flash attention: one 64-row strip per block ---------------
// grid 1024 = 32 bh x 32 strips; bh = (L&7)*4+(L>>3)&3 (XCD L2 locality);
// s = 31-(L>>5): longest strips dispatch FIRST (triangular tail self-packs).
// Ring-2 LDS (32 KB) -> 5 blocks/CU = 20 waves/CU. Per iter: wait vmcnt(0)
// (own prefetch, issued one full compute-phase earlier; K/V is L2-resident)
// -> s_barrier -> prefetch kt+1 (slot safe: all waves done with kt-1) ->
// compute kt. tile_step identical to R8 (S^T trick, lane-local softmax,
// swapped-operand PV), plus __any-guarded alpha rescale.

__global__ __launch_bounds__(256, 5) void k_attn(const u16* __restrict__ Qb,
                                                 const u16* __restrict__ Kb,
                                                 const u16* __restrict__ Vtb,
                                                 u16* __restrict__ attnb) {
    __shared__ __align__(16) u16 KV[2][2][4096];  // [slot][K/V][64x64]
    int tid = threadIdx.x;
    int w = tid >> 6, lane = tid & 63, quad = lane >> 4, l16 = lane & 15;
    int L = blockIdx.x;
    int bh = ((L & 7) << 2) | ((L >> 3) & 3);
    int s = 31 - (L >> 5);
    const u16* Qp = Qb + (size_t)bh * 131072;
    const u16* Kp = Kb + (size_t)bh * 131072;
    const u16* Vp = Vtb + (size_t)bh * 131072;
    int b = bh >> 4, h = bh & 15;

    // staging offsets (XOR-swizzled chunk layout, wave-uniform LDS base)
    int r0 = tid >> 3, c0 = ((tid & 7) ^ (r0 & 7)) * 8;
    int f1 = 256 + tid;
    int r1 = f1 >> 3, c1 = ((f1 & 7) ^ (r1 & 7)) * 8;
    int kOff0 = r0 * 64 + c0, kOff1 = r1 * 64 + c1;
    int vOff0 = r0 * 2048 + c0, vOff1 = r1 * 2048 + c1;
    int wb = (tid & ~63) * 8;

    int q_abs = s * 64 + w * 16 + l16;
    short8 qf0 = *(const short8*)&Qp[(size_t)q_abs * 64 + quad * 8];
    short8 qf1 = *(const short8*)&Qp[(size_t)q_abs * 64 + 32 + quad * 8];

    int n = s + 1;

    auto stage = [&](int j) {
        u16* Ks = (u16*)KV[j & 1][0];
        u16* Vs = (u16*)KV[j & 1][1];
        const u16* kp = Kp + (size_t)j * 4096;
        const u16* vp = Vp + (size_t)j * 64;
        async_cp16(kp + kOff0, Ks + wb);
        async_cp16(kp + kOff1, Ks + 2048 + wb);
        async_cp16(vp + vOff0, Vs + wb);
        async_cp16(vp + vOff1, Vs + 2048 + wb);
    };

    floatx4 accO[4] = {};
    float mr = NEGINF, lr = 0.f;
    int sw = l16 & 7;

    stage(0);

    for (int kt = 0; kt < n; ++kt) {
        asm volatile("s_waitcnt vmcnt(0)" ::: "memory");  // own prefetch landed
        asm volatile("s_barrier" ::: "memory");           // landed for all waves
        if (kt + 1 < n) stage(kt + 1);  // slot (kt+1)&1 free: all done with kt-1
        const u16* Ks = (const u16*)KV[kt & 1][0];
        const u16* Vs = (const u16*)KV[kt & 1][1];

        // fragments: K (A-operand of S^T MFMA), V^T (A-operand of PV MFMA)
        short8 kfa[4], kfb[4];
#pragma unroll
        for (int nt = 0; nt < 4; ++nt) {
            int rb = (nt * 16 + l16) * 8;
            kfa[nt] = *(const short8*)&Ks[(rb + (quad ^ sw)) * 8];
            kfb[nt] = *(const short8*)&Ks[(rb + ((4 + quad) ^ sw)) * 8];
        }
        short4v vf[4][4];
#pragma unroll
        for (int dt = 0; dt < 4; ++dt) {
            const char* rowb = (const char*)Vs + (dt * 16 + l16) * 128 + (quad & 1) * 8;
#pragma unroll
            for (int nt = 0; nt < 4; ++nt) {
                int chunk = nt * 2 + (quad >> 1);
                vf[nt][dt] = *(const short4v*)(rowb + ((chunk ^ sw) * 16));
            }
        }

        // S^T: lane holds S[q-row = l16 of wave][key = kt*64+nt*16+quad*4+r]
        floatx4 sa[4] = {};
#pragma unroll
        for (int nt = 0; nt < 4; ++nt) {
            sa[nt] = MFMA16(kfa[nt], qf0, sa[nt]);
            sa[nt] = MFMA16(kfb[nt], qf1, sa[nt]);
        }
        if (kt == s) {  // diagonal tile: causal mask (block-uniform branch)
#pragma unroll
            for (int nt = 0; nt < 4; ++nt)
#pragma unroll
                for (int r = 0; r < 4; ++r)
                    if (kt * 64 + nt * 16 + quad * 4 + r > q_abs)
                        sa[nt][r] = NEGINF;
        }
        // online softmax (exp2 domain); stats lane-local (q = l16 row)
        float v = sa[0][0];
#pragma unroll
        for (int nt = 0; nt < 4; ++nt)
#pragma unroll
            for (int r = 0; r < 4; ++r) v = fmaxf(v, sa[nt][r]);
        v = fmaxf(v, __shfl_xor(v, 16));
        v = fmaxf(v, __shfl_xor(v, 32));
        float m_new = fmaxf(mr, v);
        if (__any(m_new > mr)) {  // rescale only when some row's max moved
            float alpha = EXP2(mr - m_new);
            lr *= alpha;
#pragma unroll
            for (int dt = 0; dt < 4; ++dt)
#pragma unroll
                for (int r = 0; r < 4; ++r) accO[dt][r] *= alpha;
        }
        mr = m_new;
        float p[4][4];
        float rs = 0.f;
#pragma unroll
        for (int nt = 0; nt < 4; ++nt)
#pragma unroll
            for (int r = 0; r < 4; ++r) {
                float e = EXP2(sa[nt][r] - m_new);
                p[nt][r] = e;
                rs += e;
            }
        rs += __shfl_xor(rs, 16);
        rs += __shfl_xor(rs, 32);
        lr += rs;
        // PV swapped: D = (V^T frag) x (P frag) -> O[q=l16][d=dt*16+quad*4+r]
#pragma unroll
        for (int nt = 0; nt < 4; ++nt) {
            union { uint2 u; short4v s; } pf;
            pf.u.x = pkbf(p[nt][0], p[nt][1]);
            pf.u.y = pkbf(p[nt][2], p[nt][3]);
#pragma unroll
            for (int dt = 0; dt < 4; ++dt)
                accO[dt] = PV_MFMA(vf[nt][dt], pf.s, accO[dt]);
        }
    }

    // epilogue: O[q=l16][d=dt*16+quad*4+r], inv lane-local -> 8B stores
    float inv = 1.f / lr;
    size_t base = ((size_t)(b * 2048 + q_abs)) * 1024 + h * 64;
#pragma unroll
    for (int dt = 0; dt < 4; ++dt) {
        uint2 val;
        val.x = pkbf(accO[dt][0] * inv, accO[dt][1] * inv);
        val.y = pkbf(accO[dt][2] * inv, accO[dt][3] * inv);
        *(uint2*)&attnb[base + dt * 16 + quad * 4] = val;
    }
}

// ---------------- launch ----------------

extern "C" void kernel_launch(void* const* d_in, const int* in_sizes, int n_in,
                              void* d_out, int out_size, void* d_ws, size_t ws_size,
                              hipStream_t stream) {
    const float* x     = (const float*)d_in[0];
    const float* W_qkv = (const float*)d_in[1];
    const float* b_qkv = (const float*)d_in[2];
    const float* W_out = (const float*)d_in[3];
    const float* b_out = (const float*)d_in[4];
    float* out = (float*)d_out;

    char* p = (char*)d_ws;
    u16* xb    = (u16*)p; p += (size_t)4096 * 1024 * 2;     // 8 MB (reused as attn out)
    u16* wqkvT = (u16*)p; p += (size_t)3072 * 1024 * 2;     // 6 MB
    u16* woutT = (u16*)p; p += (size_t)1024 * 1024 * 2;     // 2 MB
    u16* Qb    = (u16*)p; p += (size_t)32 * 2048 * 64 * 2;  // 8 MB (pre-scaled, exp2 domain)
    u16* Kb    = (u16*)p; p += (size_t)32 * 2048 * 64 * 2;  // 8 MB
    u16* Vtb   = (u16*)p; p += (size_t)32 * 64 * 2048 * 2;  // 8 MB [bh][d][s]
    u16* attnb = xb;  // xb dead after k_qkv_gemm

    k_prep<<<6144, 256, 0, stream>>>(x, W_qkv, W_out, xb, wqkvT, woutT);
    k_qkv_gemm<<<dim3(24, 32), 256, 0, stream>>>(xb, wqkvT, b_qkv, Qb, Kb, Vtb);
    k_attn<<<1024, 256, 0, stream>>>(Qb, Kb, Vtb, attnb);
    k_out_gemm<<<dim3(8, 64), 256, 0, stream>>>(attnb, woutT, b_out, out);
}